// Round 8
// baseline (743.106 us; speedup 1.0000x reference)
//
#include <hip/hip_runtime.h>

// ConditionalCNF via MFMA (round 13): 32x32x16 restructure.
// r12 accounting: 2403 cyc/wave/stage = TRANS 768 (floor) + main ~1300 +
// MFMA 116 + DS/idle; the 16x16 b-block geometry forces 7 DS/stage with 3
// serial DS levels (z-bpermute x4 + 4x4 butterfly).  One 32x32x16 MFMA
// chain (A = full 32x32 W2, B = h1 of 32 samples, K=32 via 2 chunks) makes
// lane l and l^32 jointly own sample-cols c and c+32: z lives in registers
// (broadcast DELETED), kz = local 8-pair dot + ONE bpermute(lane^32) + add
// (butterfly DELETED).  DS 7->2/stage, main -~170/stage, MFMA 24@5 -> 12@8.
// Numerics identical to r12: hi/lo W2 on h-path, Whi-only d-path, deferred
// dlog (epilogue xor32 exchange), shared-rcp tanh, s=2log2e scaling.
//
// Layouts (HW-verified per guide m74/m101 + verified 16x16 analogs):
//   A-frag 32x32x16:  A[m=lane&31][k=(lane>>5)*8+j]
//   B-frag 32x32x16:  B[k=(lane>>5)*8+j][n=lane&31]
//   C/D:              col=lane&31, row=(reg&3)+8*(reg>>2)+4*(lane>>5)

typedef __attribute__((ext_vector_type(8))) short short8;
typedef __attribute__((ext_vector_type(2))) float float2v;
typedef __attribute__((ext_vector_type(16))) float floatx16;

constexpr int NSTEPS = 20;
constexpr float SCL = 2.8853900817779268f;   // 2*log2(e)

struct U128 { unsigned a, b, c, d; };

__device__ __forceinline__ float fexp2(float x) {
#if __has_builtin(__builtin_amdgcn_exp2f)
    return __builtin_amdgcn_exp2f(x);
#else
    return exp2f(x);
#endif
}

__device__ __forceinline__ float2v vfma(float2v a, float2v b, float2v c) {
#if __has_builtin(__builtin_elementwise_fma)
    return __builtin_elementwise_fma(a, b, c);
#else
    float2v d; d.x = fmaf(a.x, b.x, c.x); d.y = fmaf(a.y, b.y, c.y); return d;
#endif
}

// packed tanh, pre-scaled inputs xs = 2*log2(e)*x.  tanh = 1 - 2/(exp2+1),
// ONE rcp per pair via reciprocal sharing; all constants inline.
__device__ __forceinline__ float2v tanh_pk(float2v xs) {
    const float ex = fexp2(xs.x);
    const float ey = fexp2(xs.y);
    const float dx = ex + 1.0f;
    const float dy = ey + 1.0f;
    const float rr = __builtin_amdgcn_rcpf(dx * dy);
    const float q  = rr * -2.0f;
    return float2v{fmaf(q, dy, 1.0f), fmaf(q, dx, 1.0f)};
}

__device__ __forceinline__ unsigned cvtpk_bf16(float a, float b) {
    unsigned r;
    asm("v_cvt_pk_bf16_f32 %0, %1, %2" : "=v"(r) : "v"(a), "v"(b));
    return r;
}

__device__ __forceinline__ unsigned pack2bf(float a, float b) {
    unsigned ua = __builtin_bit_cast(unsigned, a) + 0x8000u;
    unsigned ub = __builtin_bit_cast(unsigned, b) + 0x8000u;
    return __builtin_amdgcn_perm(ub, ua, 0x07060302u);
}
__device__ __forceinline__ unsigned pack2bf_trunc(float2v v) {
    return __builtin_amdgcn_perm(__builtin_bit_cast(unsigned, v.y),
                                 __builtin_bit_cast(unsigned, v.x), 0x07060302u);
}
__device__ __forceinline__ float bf2f(unsigned bf) {
    return __builtin_bit_cast(float, bf << 16);
}
__device__ __forceinline__ float bperm(int addr, float x) {
    return __builtin_bit_cast(float,
        __builtin_amdgcn_ds_bpermute(addr, __builtin_bit_cast(int, x)));
}

__global__ __launch_bounds__(256, 3) void cnf_mfma(
    const float* __restrict__ Tin, const float* __restrict__ cond,
    const float* __restrict__ W1, const float* __restrict__ b1,
    const float* __restrict__ W2, const float* __restrict__ b2,
    const float* __restrict__ W3, const float* __restrict__ b3,
    float* __restrict__ out, int B)
{
    const int tid   = threadIdx.x;
    const int lane  = tid & 63;
    const int wbase = blockIdx.x * 256 + (tid >> 6) * 64;

    const int c  = lane & 31;          // D col = sample col; W2 row (A m)
    const int hi = lane >> 5;          // k-group for frags; D row-half
    const int addrX = (lane ^ 32) * 4; // row-half partner

    const float is2 = 1.0f / (SCL * SCL);

    // ---- W2 A-frags: A[m=c][k = 16t + hi*8 + j], hi/lo bf16 split ----
    short8 Whi[2], Wlo[2];
#pragma unroll
    for (int t = 0; t < 2; ++t) {
        const float* w2r = W2 + c * 32 + 16 * t + hi * 8;
        unsigned hu[4], lu[4];
#pragma unroll
        for (int p = 0; p < 4; ++p) {
            const float w0 = SCL * w2r[2 * p], w1v = SCL * w2r[2 * p + 1];
            const unsigned h0 = (__builtin_bit_cast(unsigned, w0) + 0x8000u) >> 16;
            const unsigned h1 = (__builtin_bit_cast(unsigned, w1v) + 0x8000u) >> 16;
            hu[p] = h0 | (h1 << 16);
            lu[p] = pack2bf(w0 - bf2f(h0), w1v - bf2f(h1));
        }
        Whi[t] = __builtin_bit_cast(short8, U128{hu[0], hu[1], hu[2], hu[3]});
        Wlo[t] = __builtin_bit_cast(short8, U128{lu[0], lu[1], lu[2], lu[3]});
    }

    // ---- per-lane D-row constants: u(reg) = (reg&3) + 8*(reg>>2) + 4*hi ----
    floatx16 cinit;
    float2v w3p[8];
#pragma unroll
    for (int g = 0; g < 8; ++g) {
        const int u0 = ((2 * g) & 3) + 8 * (g >> 1) + 4 * hi;
        cinit[2 * g]     = SCL * b2[u0];
        cinit[2 * g + 1] = SCL * b2[u0 + 1];
        w3p[g] = float2v{W3[u0], W3[u0 + 1]};
    }

    // ---- layer-1 constants: k(t,j) = 16t + hi*8 + j ----
    float2v w1zv[2][4];
#pragma unroll
    for (int t = 0; t < 2; ++t)
#pragma unroll
        for (int p = 0; p < 4; ++p) {
            const int k = 16 * t + hi * 8 + 2 * p;
            w1zv[t][p] = float2v{SCL * W1[k * 9], SCL * W1[(k + 1) * 9]};
        }

    int s0 = wbase + c;      if (s0 > B - 1) s0 = B - 1;
    int s1 = wbase + 32 + c; if (s1 > B - 1) s1 = B - 1;

    float cd0[8], cd1[8];
    {
        const float4* c4 = reinterpret_cast<const float4*>(cond + (size_t)s0 * 8);
        const float4 ca = c4[0], cb = c4[1];
        cd0[0]=ca.x; cd0[1]=ca.y; cd0[2]=ca.z; cd0[3]=ca.w;
        cd0[4]=cb.x; cd0[5]=cb.y; cd0[6]=cb.z; cd0[7]=cb.w;
    }
    {
        const float4* c4 = reinterpret_cast<const float4*>(cond + (size_t)s1 * 8);
        const float4 ca = c4[0], cb = c4[1];
        cd1[0]=ca.x; cd1[1]=ca.y; cd1[2]=ca.z; cd1[3]=ca.w;
        cd1[4]=cb.x; cd1[5]=cb.y; cd1[6]=cb.z; cd1[7]=cb.w;
    }

    // c1[hf][t][p]: s*(b1 + cond.W1row) for k = 16t + hi*8 + {2p,2p+1}
    float2v c1v[2][2][4];
#pragma unroll
    for (int t = 0; t < 2; ++t) {
        float c1a[8], c1b[8];
#pragma unroll
        for (int j = 0; j < 8; ++j) {
            const int k = 16 * t + hi * 8 + j;
            const float* wr = W1 + k * 9 + 1;
            float a0 = b1[k], a1 = a0;
#pragma unroll
            for (int jj = 0; jj < 8; ++jj) {
                a0 = fmaf(cd0[jj], wr[jj], a0);
                a1 = fmaf(cd1[jj], wr[jj], a1);
            }
            c1a[j] = SCL * a0;
            c1b[j] = SCL * a1;
        }
#pragma unroll
        for (int p = 0; p < 4; ++p) {
            c1v[0][t][p] = float2v{c1a[2 * p], c1a[2 * p + 1]};
            c1v[1][t][p] = float2v{c1b[2 * p], c1b[2 * p + 1]};
        }
    }

    const float b3v = b3[0];
    float z0 = Tin[s0], z1 = Tin[s1];
    float P0 = 0.0f, P1 = 0.0f;
    const float dt = 1.0f / (float)NSTEPS;
    const float2v one = {1.0f, 1.0f};
    const floatx16 zero16 = (floatx16)0.0f;

    // per-half evaluation: zi -> (az partial, dv partial) over this lane's rows
    auto half_eval = [&](float zi, const float2v (&c1h)[2][4],
                         float& azs, float& dvs) {
        unsigned bh[2][4], bd[2][4];
#pragma unroll
        for (int t = 0; t < 2; ++t)
#pragma unroll
            for (int p = 0; p < 4; ++p) {
                const float2v xs = vfma(float2v{zi, zi}, w1zv[t][p], c1h[t][p]);
                const float2v h  = tanh_pk(xs);
                bh[t][p] = cvtpk_bf16(h.x, h.y);
                const float2v hh = h * h;
                bd[t][p] = pack2bf_trunc(vfma(hh, -w1zv[t][p], w1zv[t][p]));
            }
        const short8 Bh0 = __builtin_bit_cast(short8, U128{bh[0][0], bh[0][1], bh[0][2], bh[0][3]});
        const short8 Bh1 = __builtin_bit_cast(short8, U128{bh[1][0], bh[1][1], bh[1][2], bh[1][3]});
        const short8 Bd0 = __builtin_bit_cast(short8, U128{bd[0][0], bd[0][1], bd[0][2], bd[0][3]});
        const short8 Bd1 = __builtin_bit_cast(short8, U128{bd[1][0], bd[1][1], bd[1][2], bd[1][3]});

        floatx16 Dh = __builtin_amdgcn_mfma_f32_32x32x16_bf16(Wlo[0], Bh0, cinit, 0, 0, 0);
        Dh = __builtin_amdgcn_mfma_f32_32x32x16_bf16(Whi[0], Bh0, Dh, 0, 0, 0);
        Dh = __builtin_amdgcn_mfma_f32_32x32x16_bf16(Wlo[1], Bh1, Dh, 0, 0, 0);
        Dh = __builtin_amdgcn_mfma_f32_32x32x16_bf16(Whi[1], Bh1, Dh, 0, 0, 0);
        floatx16 Dd = __builtin_amdgcn_mfma_f32_32x32x16_bf16(Whi[0], Bd0, zero16, 0, 0, 0);
        Dd = __builtin_amdgcn_mfma_f32_32x32x16_bf16(Whi[1], Bd1, Dd, 0, 0, 0);

        float2v az = {0.0f, 0.0f}, dv = {0.0f, 0.0f};
#pragma unroll
        for (int g = 0; g < 8; ++g) {
            const float2v h2 = tanh_pk(float2v{Dh[2 * g], Dh[2 * g + 1]});
            az = vfma(h2, w3p[g], az);
            const float2v ua = vfma(h2, -h2, one);
            const float2v tt = float2v{Dd[2 * g], Dd[2 * g + 1]} * w3p[g];
            dv = vfma(tt, ua, dv);
        }
        azs = az.x + az.y;
        dvs = dv.x + dv.y;
    };

    for (int step = 0; step < NSTEPS; ++step) {
        float kz0 = 0.0f, kz1 = 0.0f, accz0 = 0.0f, accz1 = 0.0f;
#pragma unroll 1
        for (int s4 = 0; s4 < 4; ++s4) {
            const float a = (s4 == 0) ? 0.0f : ((s4 == 3) ? dt : 0.5f * dt);
            const float w = ((s4 == 0) | (s4 == 3)) ? (dt * (1.0f / 6.0f))
                                                    : (dt * (1.0f / 3.0f));
            const float zi0 = fmaf(a, kz0, z0);
            const float zi1 = fmaf(a, kz1, z1);

            float az0, dv0, az1, dv1;
            half_eval(zi0, c1v[0], az0, dv0);
            half_eval(zi1, c1v[1], az1, dv1);

            // full row-sum: local 16 rows + partner's 16 rows (ONE bperm each)
            kz0 = az0 + bperm(addrX, az0) + b3v;
            kz1 = az1 + bperm(addrX, az1) + b3v;
            accz0 = fmaf(w, kz0, accz0);
            accz1 = fmaf(w, kz1, accz1);
            P0 = fmaf(w, dv0, P0);     // partner exchange deferred to epilogue
            P1 = fmaf(w, dv1, P1);
        }
        z0 += accz0;
        z1 += accz1;
    }

    // ---- epilogue: one partner exchange per half for dlog; s^-2 once ----
    const float d0 = (P0 + bperm(addrX, P0)) * is2;
    const float d1 = (P1 + bperm(addrX, P1)) * is2;

    const int sg = wbase + lane;       // lane<32 -> half0 col=lane; else half1
    if (sg < B) {
        out[sg] = hi ? z1 : z0;
        out[(size_t)B + sg] = hi ? d1 : d0;
    }
}

extern "C" void kernel_launch(void* const* d_in, const int* in_sizes, int n_in,
                              void* d_out, int out_size, void* d_ws, size_t ws_size,
                              hipStream_t stream) {
    const float* T    = (const float*)d_in[0];
    const float* cond = (const float*)d_in[1];
    const float* W1   = (const float*)d_in[2];
    const float* b1   = (const float*)d_in[3];
    const float* W2   = (const float*)d_in[4];
    const float* b2   = (const float*)d_in[5];
    const float* W3   = (const float*)d_in[6];
    const float* b3   = (const float*)d_in[7];
    float* out = (float*)d_out;

    const int B = in_sizes[0];
    const int grid = (B + 255) / 256;
    cnf_mfma<<<grid, 256, 0, stream>>>(T, cond, W1, b1, W2, b2, W3, b3, out, B);
}

// Round 10
// 729.894 us; speedup vs baseline: 1.0181x; 1.0181x over previous
//
#include <hip/hip_runtime.h>

// ConditionalCNF via MFMA (round 15): r13 structure + alias-proof permlane32
// exchange.  r14 post-mortem: the builtin permlane32_swap(x, x) fed ONE SSA
// value to BOTH tied operands; regalloc coalesced them onto one physical
// register, so the HW swapped a register's halves with itself -> both
// results = x[lane^32] -> kz = 2*partner (absmax 0.64, the observed fail).
// Fix: inline asm with two distinct "+v" read-write operands (separate
// outputs CANNOT alias), initialized a = b = x:
//   v_permlane32_swap_b32 a, b   ; a_hi <-> b_lo
//   a = {x_lo, x_lo'}: lane l<32 -> x[l],  l>=32 -> x[l-32]
//   b = {x_hi, x_hi'}: lane l<32 -> x[l+32], l>=32 -> x[l]
//   a + b = x + x[lane^32]  for every lane  (== r13's bperm sum, bitwise).
// This moves the lane^32 exchange off the LDS pipe (~100cyc) onto the VALU
// (~4cyc), 2 per s4 on the serial z-feedback chain -> attacks the ~610
// cyc/stage idle identified in r13.
//
// Layouts (HW-verified per guide m74/m101):
//   A-frag 32x32x16:  A[m=lane&31][k=(lane>>5)*8+j]
//   B-frag 32x32x16:  B[k=(lane>>5)*8+j][n=lane&31]
//   C/D:              col=lane&31, row=(reg&3)+8*(reg>>2)+4*(lane>>5)

typedef __attribute__((ext_vector_type(8))) short short8;
typedef __attribute__((ext_vector_type(2))) float float2v;
typedef __attribute__((ext_vector_type(16))) float floatx16;

constexpr int NSTEPS = 20;
constexpr float SCL = 2.8853900817779268f;   // 2*log2(e)

struct U128 { unsigned a, b, c, d; };

__device__ __forceinline__ float fexp2(float x) {
#if __has_builtin(__builtin_amdgcn_exp2f)
    return __builtin_amdgcn_exp2f(x);
#else
    return exp2f(x);
#endif
}

__device__ __forceinline__ float2v vfma(float2v a, float2v b, float2v c) {
#if __has_builtin(__builtin_elementwise_fma)
    return __builtin_elementwise_fma(a, b, c);
#else
    float2v d; d.x = fmaf(a.x, b.x, c.x); d.y = fmaf(a.y, b.y, c.y); return d;
#endif
}

// packed tanh, pre-scaled inputs xs = 2*log2(e)*x.  tanh = 1 - 2/(exp2+1),
// ONE rcp per pair via reciprocal sharing; all constants inline.
__device__ __forceinline__ float2v tanh_pk(float2v xs) {
    const float ex = fexp2(xs.x);
    const float ey = fexp2(xs.y);
    const float dx = ex + 1.0f;
    const float dy = ey + 1.0f;
    const float rr = __builtin_amdgcn_rcpf(dx * dy);
    const float q  = rr * -2.0f;
    return float2v{fmaf(q, dy, 1.0f), fmaf(q, dx, 1.0f)};
}

__device__ __forceinline__ unsigned cvtpk_bf16(float a, float b) {
    unsigned r;
    asm("v_cvt_pk_bf16_f32 %0, %1, %2" : "=v"(r) : "v"(a), "v"(b));
    return r;
}

__device__ __forceinline__ unsigned pack2bf(float a, float b) {
    unsigned ua = __builtin_bit_cast(unsigned, a) + 0x8000u;
    unsigned ub = __builtin_bit_cast(unsigned, b) + 0x8000u;
    return __builtin_amdgcn_perm(ub, ua, 0x07060302u);
}
__device__ __forceinline__ unsigned pack2bf_trunc(float2v v) {
    return __builtin_amdgcn_perm(__builtin_bit_cast(unsigned, v.y),
                                 __builtin_bit_cast(unsigned, v.x), 0x07060302u);
}
__device__ __forceinline__ float bf2f(unsigned bf) {
    return __builtin_bit_cast(float, bf << 16);
}

// x + x[lane^32] on the VALU pipe.  Two distinct "+v" outputs cannot alias;
// after v_permlane32_swap_b32 a,b (a_hi <-> b_lo), a+b is the pair-sum.
__device__ __forceinline__ float xsum32(float x) {
    float a = x, b = x;
    asm("v_permlane32_swap_b32 %0, %1" : "+v"(a), "+v"(b));
    return a + b;
}

__global__ __launch_bounds__(256, 3) void cnf_mfma(
    const float* __restrict__ Tin, const float* __restrict__ cond,
    const float* __restrict__ W1, const float* __restrict__ b1,
    const float* __restrict__ W2, const float* __restrict__ b2,
    const float* __restrict__ W3, const float* __restrict__ b3,
    float* __restrict__ out, int B)
{
    const int tid   = threadIdx.x;
    const int lane  = tid & 63;
    const int wbase = blockIdx.x * 256 + (tid >> 6) * 64;

    const int c  = lane & 31;          // D col = sample col; W2 row (A m)
    const int hi = lane >> 5;          // k-group for frags; D row-half

    const float is2 = 1.0f / (SCL * SCL);

    // ---- W2 A-frags: A[m=c][k = 16t + hi*8 + j], hi/lo bf16 split ----
    short8 Whi[2], Wlo[2];
#pragma unroll
    for (int t = 0; t < 2; ++t) {
        const float* w2r = W2 + c * 32 + 16 * t + hi * 8;
        unsigned hu[4], lu[4];
#pragma unroll
        for (int p = 0; p < 4; ++p) {
            const float w0 = SCL * w2r[2 * p], w1v = SCL * w2r[2 * p + 1];
            const unsigned h0 = (__builtin_bit_cast(unsigned, w0) + 0x8000u) >> 16;
            const unsigned h1 = (__builtin_bit_cast(unsigned, w1v) + 0x8000u) >> 16;
            hu[p] = h0 | (h1 << 16);
            lu[p] = pack2bf(w0 - bf2f(h0), w1v - bf2f(h1));
        }
        Whi[t] = __builtin_bit_cast(short8, U128{hu[0], hu[1], hu[2], hu[3]});
        Wlo[t] = __builtin_bit_cast(short8, U128{lu[0], lu[1], lu[2], lu[3]});
    }

    // ---- per-lane D-row constants: u(reg) = (reg&3) + 8*(reg>>2) + 4*hi ----
    floatx16 cinit;
    float2v w3p[8];
#pragma unroll
    for (int g = 0; g < 8; ++g) {
        const int u0 = ((2 * g) & 3) + 8 * (g >> 1) + 4 * hi;
        cinit[2 * g]     = SCL * b2[u0];
        cinit[2 * g + 1] = SCL * b2[u0 + 1];
        w3p[g] = float2v{W3[u0], W3[u0 + 1]};
    }

    // ---- layer-1 constants: k(t,j) = 16t + hi*8 + j ----
    float2v w1zv[2][4];
#pragma unroll
    for (int t = 0; t < 2; ++t)
#pragma unroll
        for (int p = 0; p < 4; ++p) {
            const int k = 16 * t + hi * 8 + 2 * p;
            w1zv[t][p] = float2v{SCL * W1[k * 9], SCL * W1[(k + 1) * 9]};
        }

    int s0 = wbase + c;      if (s0 > B - 1) s0 = B - 1;
    int s1 = wbase + 32 + c; if (s1 > B - 1) s1 = B - 1;

    float cd0[8], cd1[8];
    {
        const float4* c4 = reinterpret_cast<const float4*>(cond + (size_t)s0 * 8);
        const float4 ca = c4[0], cb = c4[1];
        cd0[0]=ca.x; cd0[1]=ca.y; cd0[2]=ca.z; cd0[3]=ca.w;
        cd0[4]=cb.x; cd0[5]=cb.y; cd0[6]=cb.z; cd0[7]=cb.w;
    }
    {
        const float4* c4 = reinterpret_cast<const float4*>(cond + (size_t)s1 * 8);
        const float4 ca = c4[0], cb = c4[1];
        cd1[0]=ca.x; cd1[1]=ca.y; cd1[2]=ca.z; cd1[3]=ca.w;
        cd1[4]=cb.x; cd1[5]=cb.y; cd1[6]=cb.z; cd1[7]=cb.w;
    }

    // c1[hf][t][p]: s*(b1 + cond.W1row) for k = 16t + hi*8 + {2p,2p+1}
    float2v c1v[2][2][4];
#pragma unroll
    for (int t = 0; t < 2; ++t) {
        float c1a[8], c1b[8];
#pragma unroll
        for (int j = 0; j < 8; ++j) {
            const int k = 16 * t + hi * 8 + j;
            const float* wr = W1 + k * 9 + 1;
            float a0 = b1[k], a1 = a0;
#pragma unroll
            for (int jj = 0; jj < 8; ++jj) {
                a0 = fmaf(cd0[jj], wr[jj], a0);
                a1 = fmaf(cd1[jj], wr[jj], a1);
            }
            c1a[j] = SCL * a0;
            c1b[j] = SCL * a1;
        }
#pragma unroll
        for (int p = 0; p < 4; ++p) {
            c1v[0][t][p] = float2v{c1a[2 * p], c1a[2 * p + 1]};
            c1v[1][t][p] = float2v{c1b[2 * p], c1b[2 * p + 1]};
        }
    }

    const float b3v = b3[0];
    float z0 = Tin[s0], z1 = Tin[s1];
    float P0 = 0.0f, P1 = 0.0f;
    const float dt = 1.0f / (float)NSTEPS;
    const float2v one = {1.0f, 1.0f};
    const floatx16 zero16 = (floatx16)0.0f;

    // per-half evaluation: zi -> (az partial, dv partial) over this lane's rows
    auto half_eval = [&](float zi, const float2v (&c1h)[2][4],
                         float& azs, float& dvs) {
        unsigned bh[2][4], bd[2][4];
#pragma unroll
        for (int t = 0; t < 2; ++t)
#pragma unroll
            for (int p = 0; p < 4; ++p) {
                const float2v xs = vfma(float2v{zi, zi}, w1zv[t][p], c1h[t][p]);
                const float2v h  = tanh_pk(xs);
                bh[t][p] = cvtpk_bf16(h.x, h.y);
                const float2v hh = h * h;
                bd[t][p] = pack2bf_trunc(vfma(hh, -w1zv[t][p], w1zv[t][p]));
            }
        const short8 Bh0 = __builtin_bit_cast(short8, U128{bh[0][0], bh[0][1], bh[0][2], bh[0][3]});
        const short8 Bh1 = __builtin_bit_cast(short8, U128{bh[1][0], bh[1][1], bh[1][2], bh[1][3]});
        const short8 Bd0 = __builtin_bit_cast(short8, U128{bd[0][0], bd[0][1], bd[0][2], bd[0][3]});
        const short8 Bd1 = __builtin_bit_cast(short8, U128{bd[1][0], bd[1][1], bd[1][2], bd[1][3]});

        floatx16 Dh = __builtin_amdgcn_mfma_f32_32x32x16_bf16(Wlo[0], Bh0, cinit, 0, 0, 0);
        Dh = __builtin_amdgcn_mfma_f32_32x32x16_bf16(Whi[0], Bh0, Dh, 0, 0, 0);
        Dh = __builtin_amdgcn_mfma_f32_32x32x16_bf16(Wlo[1], Bh1, Dh, 0, 0, 0);
        Dh = __builtin_amdgcn_mfma_f32_32x32x16_bf16(Whi[1], Bh1, Dh, 0, 0, 0);
        floatx16 Dd = __builtin_amdgcn_mfma_f32_32x32x16_bf16(Whi[0], Bd0, zero16, 0, 0, 0);
        Dd = __builtin_amdgcn_mfma_f32_32x32x16_bf16(Whi[1], Bd1, Dd, 0, 0, 0);

        float2v az = {0.0f, 0.0f}, dv = {0.0f, 0.0f};
#pragma unroll
        for (int g = 0; g < 8; ++g) {
            const float2v h2 = tanh_pk(float2v{Dh[2 * g], Dh[2 * g + 1]});
            az = vfma(h2, w3p[g], az);
            const float2v ua = vfma(h2, -h2, one);
            const float2v tt = float2v{Dd[2 * g], Dd[2 * g + 1]} * w3p[g];
            dv = vfma(tt, ua, dv);
        }
        azs = az.x + az.y;
        dvs = dv.x + dv.y;
    };

    for (int step = 0; step < NSTEPS; ++step) {
        float kz0 = 0.0f, kz1 = 0.0f, accz0 = 0.0f, accz1 = 0.0f;
#pragma unroll 1
        for (int s4 = 0; s4 < 4; ++s4) {
            const float a = (s4 == 0) ? 0.0f : ((s4 == 3) ? dt : 0.5f * dt);
            const float w = ((s4 == 0) | (s4 == 3)) ? (dt * (1.0f / 6.0f))
                                                    : (dt * (1.0f / 3.0f));
            const float zi0 = fmaf(a, kz0, z0);
            const float zi1 = fmaf(a, kz1, z1);

            float az0, dv0, az1, dv1;
            half_eval(zi0, c1v[0], az0, dv0);
            half_eval(zi1, c1v[1], az1, dv1);

            // full row-sum: self + lane^32 partner, VALU-pipe exchange
            kz0 = xsum32(az0) + b3v;
            kz1 = xsum32(az1) + b3v;
            accz0 = fmaf(w, kz0, accz0);
            accz1 = fmaf(w, kz1, accz1);
            P0 = fmaf(w, dv0, P0);     // partner exchange deferred to epilogue
            P1 = fmaf(w, dv1, P1);
        }
        z0 += accz0;
        z1 += accz1;
    }

    // ---- epilogue: one partner exchange per half for dlog; s^-2 once ----
    const float d0 = xsum32(P0) * is2;
    const float d1 = xsum32(P1) * is2;

    const int sg = wbase + lane;       // lane<32 -> half0 col=lane; else half1
    if (sg < B) {
        out[sg] = hi ? z1 : z0;
        out[(size_t)B + sg] = hi ? d1 : d0;
    }
}

extern "C" void kernel_launch(void* const* d_in, const int* in_sizes, int n_in,
                              void* d_out, int out_size, void* d_ws, size_t ws_size,
                              hipStream_t stream) {
    const float* T    = (const float*)d_in[0];
    const float* cond = (const float*)d_in[1];
    const float* W1   = (const float*)d_in[2];
    const float* b1   = (const float*)d_in[3];
    const float* W2   = (const float*)d_in[4];
    const float* b2   = (const float*)d_in[5];
    const float* W3   = (const float*)d_in[6];
    const float* b3   = (const float*)d_in[7];
    float* out = (float*)d_out;

    const int B = in_sizes[0];
    const int grid = (B + 255) / 256;
    cnf_mfma<<<grid, 256, 0, stream>>>(T, cond, W1, b1, W2, b2, W3, b3, out, B);
}